// Round 19
// baseline (241.251 us; speedup 1.0000x reference)
//
#include <hip/hip_runtime.h>
#include <stdint.h>

typedef unsigned short u16;
typedef __attribute__((ext_vector_type(8))) short short8;   // 8 bf16 (MFMA A/B frag)
typedef __attribute__((ext_vector_type(4))) float floatx4;  // MFMA C/D frag

__device__ inline float b2f(u16 u) {
  union { uint32_t i; float f; } x; x.i = ((uint32_t)u) << 16; return x.f;
}
__device__ inline u16 f2b(float f) {
  union { float f; uint32_t i; } x; x.f = f;
  uint32_t r = (x.i + 0x7FFFu + ((x.i >> 16) & 1u)) >> 16;
  return (u16)r;
}
__device__ inline float gelu_f(float v) {
  return 0.5f * v * (1.0f + erff(v * 0.70710678118654752440f));
}

#define MFMA16(a, b, c) __builtin_amdgcn_mfma_f32_16x16x32_bf16((a), (b), (c), 0, 0, 0)

// async global->LDS, 16B per lane; LDS dest must be wave-uniform base + lane*16
__device__ __forceinline__ void gl2lds16(const u16* g, u16* l) {
  __builtin_amdgcn_global_load_lds(
      (const __attribute__((address_space(1))) uint32_t*)(uintptr_t)g,
      (__attribute__((address_space(3))) uint32_t*)(uint32_t)(uintptr_t)l,
      16, 0, 0);
}

// ------------- batched transpose+convert of all 5 weights (fp32 -> bf16^T) -------
// Wl is stored SIGMA-PLANE ordered: wlt[(d>>5)*4096 + c*32 + sig(d&31)] so the
// fused attn epilogue can read A-fragments from 32-k planes (kbuf pattern) and
// stage it linearly via global_load_lds.
__global__ __launch_bounds__(256)
void tpose_all_kernel(const float* __restrict__ W1, const float* __restrict__ W2,
                      const float* __restrict__ Wqkv, const float* __restrict__ Wl,
                      const float* __restrict__ Wo,
                      u16* __restrict__ w1t, u16* __restrict__ w2t,
                      u16* __restrict__ wqkvt, u16* __restrict__ wlt,
                      u16* __restrict__ wot) {
  int id = blockIdx.x;
  const float* src; u16* dst; int R, C, bx, by, kind = 0;
  if (id < 2304)      { src = W2;   dst = w2t;   R = 1536; C = 1536; bx = (id % 48) * 32; by = (id / 48) * 32; }
  else if (id < 2496) { id -= 2304; src = W1;   dst = w1t;   R = 128;  C = 1536; bx = (id % 48) * 32; by = (id / 48) * 32; }
  else if (id < 2688) { id -= 2496; src = Wo;   dst = wot;   R = 1536; C = 128;  bx = (id % 4) * 32;  by = (id / 4) * 32; }
  else if (id < 2736) { id -= 2688; src = Wqkv; dst = wqkvt; R = 128;  C = 384;  bx = (id % 12) * 32; by = (id / 12) * 32; }
  else                { id -= 2736; src = Wl;   dst = wlt;   R = 128;  C = 128;  bx = (id % 4) * 32;  by = (id / 4) * 32; kind = 1; }
  __shared__ u16 t[32][33];
  int tx = threadIdx.x & 31, ty = threadIdx.x >> 5;
  for (int i = 0; i < 32; i += 8)
    t[ty + i][tx] = f2b(src[(size_t)(by + ty + i) * C + bx + tx]);
  __syncthreads();
  if (kind == 0) {
    for (int i = 0; i < 32; i += 8)
      dst[(size_t)(bx + ty + i) * R + by + tx] = t[tx][ty + i];
  } else {
    // value = Wl[d=by+tx][c=bx+ty+i] -> plane (by>>5), row c, pos sig(tx)
    int sig = ((tx >> 2) & 3) * 8 + ((tx >> 4) & 1) * 4 + (tx & 3);
    for (int i = 0; i < 32; i += 8)
      dst[(size_t)(by >> 5) * 4096 + (size_t)(bx + ty + i) * 32 + sig] = t[tx][ty + i];
  }
}

// ------------- LayerNorm D=128, fp32 source -> bf16 out; one wave per row ---------
__global__ __launch_bounds__(256)
void ln128_f32_kernel(const float* __restrict__ X, const float* __restrict__ g,
                      const float* __restrict__ bb, u16* __restrict__ Y) {
  int tid = threadIdx.x, w = tid >> 6, lane = tid & 63;
  int row = blockIdx.x * 4 + w;
  const float* xr = X + (size_t)row * 128;
  float2 xv = *(const float2*)(xr + lane * 2);
  float x0 = xv.x, x1 = xv.y;
  float s = x0 + x1, s2 = x0 * x0 + x1 * x1;
  for (int m = 1; m < 64; m <<= 1) { s += __shfl_xor(s, m, 64); s2 += __shfl_xor(s2, m, 64); }
  float mean = s * (1.0f / 128.0f);
  float var = s2 * (1.0f / 128.0f) - mean * mean;
  float rstd = 1.0f / sqrtf(var + 1e-5f);
  float2 gv = *(const float2*)(g + lane * 2);
  float2 bv = *(const float2*)(bb + lane * 2);
  float y0 = (x0 - mean) * rstd * gv.x + bv.x;
  float y1 = (x1 - mean) * rstd * gv.y + bv.y;
  *(uint32_t*)(Y + (size_t)row * 128 + lane * 2) =
      (uint32_t)f2b(y0) | ((uint32_t)f2b(y1) << 16);
}

// ------------- LayerNorm D=1536, bf16 source -> bf16 out; one block per row -------
__global__ __launch_bounds__(256)
void ln1536_kernel(const u16* __restrict__ X, const float* __restrict__ g,
                   const float* __restrict__ bb, u16* __restrict__ Y) {
  int row = blockIdx.x, tid = threadIdx.x;
  const u16* xr = X + (size_t)row * 1536;
  uint32_t u0 = *(const uint32_t*)(xr + tid * 6);
  uint32_t u1 = *(const uint32_t*)(xr + tid * 6 + 2);
  uint32_t u2 = *(const uint32_t*)(xr + tid * 6 + 4);
  float v[6] = { b2f(u0 & 0xffff), b2f(u0 >> 16), b2f(u1 & 0xffff),
                 b2f(u1 >> 16),    b2f(u2 & 0xffff), b2f(u2 >> 16) };
  float s = 0.f, s2 = 0.f;
  for (int j = 0; j < 6; j++) { s += v[j]; s2 += v[j] * v[j]; }
  for (int m = 1; m < 64; m <<= 1) { s += __shfl_xor(s, m, 64); s2 += __shfl_xor(s2, m, 64); }
  __shared__ float red[8];
  int w = tid >> 6, lane = tid & 63;
  if (lane == 0) { red[w] = s; red[4 + w] = s2; }
  __syncthreads();
  s = red[0] + red[1] + red[2] + red[3];
  s2 = red[4] + red[5] + red[6] + red[7];
  float mean = s * (1.0f / 1536.0f);
  float var = s2 * (1.0f / 1536.0f) - mean * mean;
  float rstd = 1.0f / sqrtf(var + 1e-5f);
  uint32_t o[3];
  for (int p = 0; p < 3; p++) {
    int c = tid * 6 + p * 2;
    float y0 = (v[p * 2] - mean) * rstd * g[c] + bb[c];
    float y1 = (v[p * 2 + 1] - mean) * rstd * g[c + 1] + bb[c + 1];
    o[p] = (uint32_t)f2b(y0) | ((uint32_t)f2b(y1) << 16);
  }
  u16* yr = Y + (size_t)row * 1536 + tid * 6;
  *(uint32_t*)(yr) = o[0];
  *(uint32_t*)(yr + 2) = o[1];
  *(uint32_t*)(yr + 4) = o[2];
}

// ------------- QKV GEMM 128x128 tile, PIPELINED (dbuf, single barrier/K-step) -----
__global__ __launch_bounds__(256)
void qkv_kernel(const u16* __restrict__ A, const u16* __restrict__ BT,
                const float* __restrict__ bias, u16* __restrict__ qkv,
                u16* __restrict__ vT) {
  const int K = 128;
  __shared__ __align__(16) u16 abuf[2 * 128 * 32];
  __shared__ __align__(16) u16 bbuf[2 * 128 * 32];
  int tid = threadIdx.x;
  int w = tid >> 6, lane = tid & 63, ln = lane & 15, quad = lane >> 4;
  int bm = blockIdx.x * 128, bn = blockIdx.y * 128;
  int wr = w >> 1, wc = w & 1;
  floatx4 acc[4][4] = {};
  auto STAGE = [&](int k0, int buf) {
    u16* ab = abuf + buf * 4096;
    u16* bb = bbuf + buf * 4096;
    for (int rd = 0; rd < 2; rd++) {
      int c = tid + rd * 256;
      int row = c >> 2, col = (c & 3) * 8;
      gl2lds16(A + (size_t)(bm + row) * K + k0 + col, ab + c * 8);
      gl2lds16(BT + (size_t)(bn + row) * K + k0 + col, bb + c * 8);
    }
  };
  STAGE(0, 0);
  int it = 0;
  for (int k0 = 0; k0 < K; k0 += 32, it++) {
    __syncthreads();                      // staged tile (it&1) ready
    if (k0 + 32 < K) STAGE(k0 + 32, (it + 1) & 1);
    const u16* ab = abuf + (it & 1) * 4096;
    const u16* bb = bbuf + (it & 1) * 4096;
    short8 af[4], bf[4];
    for (int i = 0; i < 4; i++)
      af[i] = *(const short8*)(ab + (wr * 64 + i * 16 + ln) * 32 + quad * 8);
    for (int j = 0; j < 4; j++)
      bf[j] = *(const short8*)(bb + (wc * 64 + j * 16 + ln) * 32 + quad * 8);
    for (int i = 0; i < 4; i++)
      for (int j = 0; j < 4; j++)
        acc[i][j] = MFMA16(af[i], bf[j], acc[i][j]);
  }
  if (blockIdx.y < 2) {
    const float QSCALE = 0.08838834764831845f * 1.4426950408889634f;
    float scale = (blockIdx.y == 0) ? QSCALE : 1.0f;
    for (int i = 0; i < 4; i++) {
      int row0 = bm + wr * 64 + i * 16 + quad * 4;
      for (int j = 0; j < 4; j++) {
        int col = bn + wc * 64 + j * 16 + ln;
        float bv = bias[col];
        for (int r = 0; r < 4; r++)
          qkv[(size_t)(row0 + r) * 256 + col] = f2b((acc[i][j][r] + bv) * scale);
      }
    }
  } else {
    int bh = bm >> 10;                 // block fully inside one (b,h): 1024 rows/bh
    int nb = bm & 1023;
    u16* vp = vT + (size_t)bh * 128 * 1024;
    for (int i = 0; i < 4; i++) {
      int n0 = nb + wr * 64 + i * 16 + quad * 4;
      // sigma-interleaved position within the 32-key group:
      int npos = (n0 & ~31) | (((n0 >> 2) & 3) * 8) | (((n0 >> 4) & 1) * 4);
      for (int j = 0; j < 4; j++) {
        int d = wc * 64 + j * 16 + ln;
        float bv = bias[256 + d];
        u16 tmp[4];
        for (int r = 0; r < 4; r++) tmp[r] = f2b(acc[i][j][r] + bv);
        *(uint2*)(vp + (size_t)d * 1024 + npos) = *(const uint2*)tmp;
      }
    }
  }
}

// ------------- GEMM 64x128 tile, BK=32 (W1), PIPELINED ----------------------------
template <int GELU, int RES, typename OUTT>
__global__ __launch_bounds__(256)
void gemm64_kernel(const u16* __restrict__ A, const u16* __restrict__ BT,
                   const float* __restrict__ bias, const u16* __restrict__ res,
                   OUTT* __restrict__ C, int M, int N, int K) {
  __shared__ __align__(16) u16 abuf[2 * 64 * 32];
  __shared__ __align__(16) u16 bbuf[2 * 128 * 32];
  int tid = threadIdx.x;
  int w = tid >> 6, lane = tid & 63, ln = lane & 15, quad = lane >> 4;
  int bm = blockIdx.x * 64, bn = blockIdx.y * 128;
  floatx4 acc[4][2] = {};
  auto STAGE = [&](int k0, int buf) {
    u16* ab = abuf + buf * 2048;
    u16* bb = bbuf + buf * 4096;
    for (int rd = 0; rd < 2; rd++) {
      int c = tid + rd * 256;
      int row = c >> 2, col = (c & 3) * 8;
      gl2lds16(BT + (size_t)(bn + row) * K + k0 + col, bb + c * 8);
    }
    {
      int c = tid;
      int row = c >> 2, col = (c & 3) * 8;
      gl2lds16(A + (size_t)(bm + row) * K + k0 + col, ab + c * 8);
    }
  };
  STAGE(0, 0);
  int it = 0;
  for (int k0 = 0; k0 < K; k0 += 32, it++) {
    __syncthreads();
    if (k0 + 32 < K) STAGE(k0 + 32, (it + 1) & 1);
    const u16* ab = abuf + (it & 1) * 2048;
    const u16* bb = bbuf + (it & 1) * 4096;
    short8 af[4], bf[2];
    for (int i = 0; i < 4; i++)
      af[i] = *(const short8*)(ab + (i * 16 + ln) * 32 + quad * 8);
    for (int j = 0; j < 2; j++)
      bf[j] = *(const short8*)(bb + (w * 32 + j * 16 + ln) * 32 + quad * 8);
    for (int i = 0; i < 4; i++)
      for (int j = 0; j < 2; j++)
        acc[i][j] = MFMA16(af[i], bf[j], acc[i][j]);
  }
  for (int i = 0; i < 4; i++) {
    int row0 = bm + i * 16 + quad * 4;
    for (int j = 0; j < 2; j++) {
      int col = bn + w * 32 + j * 16 + ln;
      float bv = bias[col];
      for (int r = 0; r < 4; r++) {
        float v = acc[i][j][r] + bv;
        if (RES) v += b2f(res[(size_t)(row0 + r) * N + col]);
        if (GELU) v = gelu_f(v);
        if constexpr (sizeof(OUTT) == 2)
          C[(size_t)(row0 + r) * N + col] = f2b(v);
        else
          C[(size_t)(row0 + r) * N + col] = v;
      }
    }
  }
}

// ------------- GEMM 64x128 tile, BK=64 (W2), PIPELINED + FUSED per-head LN --------
__global__ __launch_bounds__(256)
void gemm64b_ln_kernel(const u16* __restrict__ A, const u16* __restrict__ BT,
                       const float* __restrict__ bias, u16* __restrict__ C,
                       const float* __restrict__ lng, const float* __restrict__ lnb,
                       u16* __restrict__ aln, int M, int N, int K) {
  __shared__ __align__(16) u16 abuf[2 * 2 * 64 * 32];
  __shared__ __align__(16) u16 bbuf[2 * 2 * 128 * 32];
  int tid = threadIdx.x;
  int w = tid >> 6, lane = tid & 63, ln = lane & 15, quad = lane >> 4;
  int bm = blockIdx.x * 64, bn = blockIdx.y * 128;
  floatx4 acc[4][2] = {};
  auto STAGE = [&](int k0, int buf) {
    u16* ab = abuf + buf * 4096;
    u16* bb = bbuf + buf * 8192;
    for (int ks = 0; ks < 2; ks++) {
      {
        int c = tid;
        int row = c >> 2, cc = c & 3;
        gl2lds16(A + (size_t)(bm + row) * K + k0 + ks * 32 + cc * 8,
                 ab + ks * 2048 + c * 8);
      }
      for (int rd = 0; rd < 2; rd++) {
        int c = tid + rd * 256;
        int row = c >> 2, cc = c & 3;
        gl2lds16(BT + (size_t)(bn + row) * K + k0 + ks * 32 + cc * 8,
                 bb + ks * 4096 + c * 8);
      }
    }
  };
  STAGE(0, 0);
  int it = 0;
  for (int k0 = 0; k0 < K; k0 += 64, it++) {
    __syncthreads();
    if (k0 + 64 < K) STAGE(k0 + 64, (it + 1) & 1);
    const u16* ab = abuf + (it & 1) * 4096;
    const u16* bb = bbuf + (it & 1) * 8192;
    short8 af[2][4], bf[2][2];
    for (int ks = 0; ks < 2; ks++) {
      for (int i = 0; i < 4; i++)
        af[ks][i] = *(const short8*)(ab + ks * 2048 + (i * 16 + ln) * 32 + quad * 8);
      for (int j = 0; j < 2; j++)
        bf[ks][j] = *(const short8*)(bb + ks * 4096 + (w * 32 + j * 16 + ln) * 32 + quad * 8);
    }
    for (int i = 0; i < 4; i++)
      for (int j = 0; j < 2; j++) {
        acc[i][j] = MFMA16(af[0][i], bf[0][j], acc[i][j]);
        acc[i][j] = MFMA16(af[1][i], bf[1][j], acc[i][j]);
      }
  }
  // epilogue: write h2 (bf16) + fused per-head LN -> aln
  float vr[4][2][4];
  float sl[16], s2l[16];
  for (int t = 0; t < 16; t++) { sl[t] = 0.f; s2l[t] = 0.f; }
  float g0 = lng[w * 32 + ln], g1 = lng[w * 32 + 16 + ln];
  float bb0 = lnb[w * 32 + ln], bb1 = lnb[w * 32 + 16 + ln];
  for (int i = 0; i < 4; i++) {
    int row0 = bm + i * 16 + quad * 4;
    for (int j = 0; j < 2; j++) {
      int col = bn + w * 32 + j * 16 + ln;
      float bv = bias[col];
      for (int r = 0; r < 4; r++) {
        u16 hb = f2b(acc[i][j][r] + bv);
        C[(size_t)(row0 + r) * N + col] = hb;
        float x = b2f(hb);
        vr[i][j][r] = x;
        sl[i * 4 + r] += x;
        s2l[i * 4 + r] += x * x;
      }
    }
  }
  // reduce over ln (stays within quad: masks < 16)
  for (int m = 1; m < 16; m <<= 1)
    for (int t = 0; t < 16; t++) {
      sl[t] += __shfl_xor(sl[t], m, 64);
      s2l[t] += __shfl_xor(s2l[t], m, 64);
    }
  // cross-wave reduce via LDS (abuf dead; ensure all waves done reading frags)
  __syncthreads();
  float* red = (float*)abuf;                 // [2][4 w][64 row] = 2KB
  if (ln == 0) {
    for (int i = 0; i < 4; i++)
      for (int r = 0; r < 4; r++) {
        int row = i * 16 + quad * 4 + r;
        red[w * 64 + row] = sl[i * 4 + r];
        red[256 + w * 64 + row] = s2l[i * 4 + r];
      }
  }
  __syncthreads();
  int hh = bn >> 7;
  for (int i = 0; i < 4; i++) {
    int row0 = bm + i * 16 + quad * 4;
    int rowl = i * 16 + quad * 4;
    for (int r = 0; r < 4; r++) {
      float s = red[rowl + r] + red[64 + rowl + r] + red[128 + rowl + r] + red[192 + rowl + r];
      float s2 = red[256 + rowl + r] + red[320 + rowl + r] + red[384 + rowl + r] + red[448 + rowl + r];
      float mean = s * (1.0f / 128.0f);
      float var = s2 * (1.0f / 128.0f) - mean * mean;
      float rstd = 1.0f / sqrtf(var + 1e-5f);
      int rw = row0 + r, b = rw >> 10, n = rw & 1023;
      size_t arow = ((size_t)(b * 12 + hh) * 1024 + n) * 128;
      float y0 = (vr[i][0][r] - mean) * rstd * g0 + bb0;
      float y1 = (vr[i][1][r] - mean) * rstd * g1 + bb1;
      aln[arow + w * 32 + ln] = f2b(y0);
      aln[arow + w * 32 + 16 + ln] = f2b(y1);
    }
  }
}

// ------------- Wo split-K partial: 64x128 tile, part p = blockIdx.y, PIPELINED ----
__global__ __launch_bounds__(256)
void gemm64_part_kernel(const u16* __restrict__ A, const u16* __restrict__ BT,
                        float* __restrict__ pws, int Kfull, int kspan) {
  __shared__ __align__(16) u16 abuf[2 * 64 * 32];
  __shared__ __align__(16) u16 bbuf[2 * 128 * 32];
  int tid = threadIdx.x;
  int w = tid >> 6, lane = tid & 63, ln = lane & 15, quad = lane >> 4;
  int bm = blockIdx.x * 64;
  int kbeg = blockIdx.y * kspan, kend = kbeg + kspan;
  float* Cp = pws + (size_t)blockIdx.y * 4096 * 128;
  floatx4 acc[4][2] = {};
  auto STAGE = [&](int k0, int buf) {
    u16* ab = abuf + buf * 2048;
    u16* bb = bbuf + buf * 4096;
    for (int rd = 0; rd < 2; rd++) {
      int c = tid + rd * 256;
      int row = c >> 2, col = (c & 3) * 8;
      gl2lds16(BT + (size_t)row * Kfull + k0 + col, bb + c * 8);
    }
    {
      int c = tid;
      int row = c >> 2, col = (c & 3) * 8;
      gl2lds16(A + (size_t)(bm + row) * Kfull + k0 + col, ab + c * 8);
    }
  };
  STAGE(kbeg, 0);
  int it = 0;
  for (int k0 = kbeg; k0 < kend; k0 += 32, it++) {
    __syncthreads();
    if (k0 + 32 < kend) STAGE(k0 + 32, (it + 1) & 1);
    const u16* ab = abuf + (it & 1) * 2048;
    const u16* bb = bbuf + (it & 1) * 4096;
    short8 af[4], bf[2];
    for (int i = 0; i < 4; i++)
      af[i] = *(const short8*)(ab + (i * 16 + ln) * 32 + quad * 8);
    for (int j = 0; j < 2; j++)
      bf[j] = *(const short8*)(bb + (w * 32 + j * 16 + ln) * 32 + quad * 8);
    for (int i = 0; i < 4; i++)
      for (int j = 0; j < 2; j++)
        acc[i][j] = MFMA16(af[i], bf[j], acc[i][j]);
  }
  for (int i = 0; i < 4; i++) {
    int row0 = bm + i * 16 + quad * 4;
    for (int j = 0; j < 2; j++) {
      int col = w * 32 + j * 16 + ln;
      for (int r = 0; r < 4; r++)
        Cp[(size_t)(row0 + r) * 128 + col] = acc[i][j][r];
    }
  }
}

// combine 4 split-K partials + bias + gelu -> fp32 out  (4096*128 elems)
__global__ __launch_bounds__(256)
void combine_wo_kernel(const float* __restrict__ p, const float* __restrict__ bias,
                       float* __restrict__ out) {
  int i = blockIdx.x * 256 + threadIdx.x;
  const int SZ = 4096 * 128;
  float v = p[i] + p[i + SZ] + p[i + 2 * SZ] + p[i + 3 * SZ] + bias[i & 127];
  out[i] = gelu_f(v);
}

// ------------- Flash attention + FUSED Wl GEMM epilogue --------------------------
// Main loop: round-11 verified. Epilogue computes feats = gelu(O*Wl + bias + res).
// wlt (sigma-plane) staged via LDS at B3/B4 (round-15 verified config).
// Round-19: s_setprio(1) around the MFMA clusters (QK^T; l9+PV) — T5. With 3
// independent blocks/CU at different kt phases the CU scheduler can favor the
// MFMA-issuing wave (catalog: +4-7% on attn-shaped kernels). Hint-only change.
__global__ __launch_bounds__(256, 3)
void attn_kernel(const u16* __restrict__ qkv, const u16* __restrict__ vT,
                 const u16* __restrict__ wlt, const float* __restrict__ blp,
                 const u16* __restrict__ h2res, u16* __restrict__ feats) {
  int blk = blockIdx.x;
  int xcd = blk & 7, slot = blk >> 3;
  int bh = xcd * 6 + (slot >> 4);
  int qt = slot & 15;
  int tid = threadIdx.x, w = tid >> 6, lane = tid & 63, ln = lane & 15, quad = lane >> 4;
  int pair = w & 1, half = w >> 1;
  __shared__ __align__(16) u16 smem[24576 + 128];
  u16* kbuf = smem;                   // [4 st][64 key][32]
  u16* vbufs = smem + 8192;           // 2 x [2 kf][128 d][32 pos] (sigma order)
  const int rs = 256;
  size_t base = (size_t)bh * 1024 * 256;
  const u16* qp = qkv + base;
  const u16* kp = qkv + base + 128;
  const u16* vp = vT + (size_t)bh * 128 * 1024;

  // Q fragments for this wave's 32 q rows (2 groups of 16)
  short8 qf[2][4];
  for (int g = 0; g < 2; g++) {
    int qrow = qt * 64 + pair * 32 + g * 16 + ln;
    for (int st = 0; st < 4; st++)
      qf[g][st] = *(const short8*)(qp + (size_t)qrow * rs + st * 32 + quad * 8);
  }

  // ones A-row fragment: A[0][k]=1 (lanes with ln==0), other rows 0.
  short8 onesA;
  {
    short v = (ln == 0) ? (short)0x3F80 : (short)0;
    for (int j = 0; j < 8; j++) onesA[j] = v;
  }

  floatx4 o[2][8] = {};             // O^T partial: [g][dt], row=d quad*4+r, col=q=ln
  floatx4 l9[2] = {};               // row0 = per-q P-sums (ones-MFMA)

  // staging helpers: 4 chunks each per thread per tile (all linear)
  auto STAGE_K = [&](int kt) {
    for (int it = 0; it < 4; it++) {
      int c = it * 256 + tid;
      int st = c >> 8, key = (c >> 2) & 63, cc = c & 3;
      gl2lds16(kp + (size_t)(kt * 64 + key) * rs + st * 32 + cc * 8, kbuf + c * 8);
    }
  };
  auto STAGE_V = [&](int kt, int buf) {
    u16* vb = vbufs + buf * 8192;
    for (int it = 0; it < 4; it++) {
      int c = it * 256 + tid;
      int kf = c >> 9, d = (c >> 2) & 127, cc = c & 3;
      gl2lds16(vp + (size_t)d * 1024 + kt * 64 + kf * 32 + cc * 8, vb + c * 8);
    }
  };

  STAGE_K(0);
  STAGE_V(0, 0);

  for (int kt = 0; kt < 16; kt++) {
    __syncthreads();                 // drains vmcnt(0): staging for kt complete

    // K fragments -> registers (frees kbuf for next-tile staging)
    short8 kfr[2][4];
    for (int tt = 0; tt < 2; tt++)
      for (int st = 0; st < 4; st++)
        kfr[tt][st] = *(const short8*)(kbuf + st * 2048 +
                                       ((half * 2 + tt) * 16 + ln) * 32 + quad * 8);
    __syncthreads();                 // all waves done reading kbuf (lgkm drained)

    if (kt < 15) {                   // async staging overlaps the compute below
      STAGE_K(kt + 1);
      STAGE_V(kt + 1, (kt + 1) & 1);
    }

    // S^T tiles from registers (q pre-scaled -> S already in log2 units)
    __builtin_amdgcn_s_setprio(1);
    floatx4 s[2][2] = {};            // [g][tt]
    for (int tt = 0; tt < 2; tt++)
      for (int st = 0; st < 4; st++) {
        s[0][tt] = MFMA16(kfr[tt][st], qf[0][st], s[0][tt]);
        s[1][tt] = MFMA16(kfr[tt][st], qf[1][st], s[1][tt]);
      }
    __builtin_amdgcn_s_setprio(0);

    // exp2 -> packed bf16; natural order IS the PV B-operand (sigma ordering)
    short8 pfrag[2];
    for (int g = 0; g < 2; g++) {
      float p0[4], p1[4];
      for (int r = 0; r < 4; r++) {
        p0[r] = exp2f(s[g][0][r]);
        p1[r] = exp2f(s[g][1][r]);
      }
      uint32_t a0, a1, b0, b1;
      asm("v_cvt_pk_bf16_f32 %0, %1, %2" : "=v"(a0) : "v"(p0[0]), "v"(p0[1]));
      asm("v_cvt_pk_bf16_f32 %0, %1, %2" : "=v"(a1) : "v"(p0[2]), "v"(p0[3]));
      asm("v_cvt_pk_bf16_f32 %0, %1, %2" : "=v"(b0) : "v"(p1[0]), "v"(p1[1]));
      asm("v_cvt_pk_bf16_f32 %0, %1, %2" : "=v"(b1) : "v"(p1[2]), "v"(p1[3]));
      union { uint32_t u[4]; short8 v; } pu;
      pu.u[0] = a0; pu.u[1] = a1; pu.u[2] = b0; pu.u[3] = b1;
      pfrag[g] = pu.v;
    }

    // row-sums + PV on the MFMA pipe
    __builtin_amdgcn_s_setprio(1);
    l9[0] = MFMA16(onesA, pfrag[0], l9[0]);
    l9[1] = MFMA16(onesA, pfrag[1], l9[1]);

    // PV: single b128 V^T A-fragment (vT stored in sigma order)
    const u16* vb = vbufs + (kt & 1) * 8192;
    for (int dt = 0; dt < 8; dt++) {
      short8 av = *(const short8*)(vb + half * 4096 + (dt * 16 + ln) * 32 + quad * 8);
      o[0][dt] = MFMA16(av, pfrag[0], o[0][dt]);
      o[1][dt] = MFMA16(av, pfrag[1], o[1][dt]);
    }
    __builtin_amdgcn_s_setprio(0);
  }

  // per-q row-sums live at quad0/r0, col=ln -> broadcast from lane ln
  float lsum[2];
  lsum[0] = __shfl(l9[0][0], ln);
  lsum[1] = __shfl(l9[1][0], ln);

  // ---- merge key-halves, then fused Wl GEMM ----
  __syncthreads();                             // B1: kbuf/vbuf dead
  float* mbuf = (float*)smem;                  // [2 pair][128 d][32 q(rot)] 32KB
  float* lbuf = (float*)(smem + 16384);        // 256B at byte 32768
  u16* obf = smem + 16512;                     // 4 planes x [64 q][32 pos] 16KB
  if (half == 1) {
    float* mp = mbuf + pair * 4096;
    for (int g = 0; g < 2; g++)
      for (int dt = 0; dt < 8; dt++)
        for (int r = 0; r < 4; r++)
          mp[(dt * 16 + quad * 4 + r) * 32 + ((g * 16 + ln + quad * 8) & 31)] = o[g][dt][r];
    if (quad == 0) {
      lbuf[pair * 32 + ln] = lsum[0];
      lbuf[pair * 32 + 16 + ln] = lsum[1];
    }
  }
  __syncthreads();                             // B2: mbuf/lbuf ready
  if (half == 0) {
    float* mp = mbuf + pair * 4096;
    for (int g = 0; g < 2; g++) {
      float lt = lsum[g] + lbuf[pair * 32 + g * 16 + ln];
      float inv = 1.0f / lt;
      int q = pair * 32 + g * 16 + ln;
      for (int dt = 0; dt < 8; dt++) {
        float vv[4];
        for (int r = 0; r < 4; r++)
          vv[r] = (o[g][dt][r] +
                   mp[(dt * 16 + quad * 4 + r) * 32 + ((g * 16 + ln + quad * 8) & 31)]) * inv;
        uint32_t w0, w1;
        asm("v_cvt_pk_bf16_f32 %0, %1, %2" : "=v"(w0) : "v"(vv[0]), "v"(vv[1]));
        asm("v_cvt_pk_bf16_f32 %0, %1, %2" : "=v"(w1) : "v"(vv[2]), "v"(vv[3]));
        uint2 pk; pk.x = w0; pk.y = w1;
        // plane kk=dt>>1, row q, pos quad*8 + (dt&1)*4  (sigma-local of d)
        *(uint2*)(obf + (dt >> 1) * 2048 + q * 32 + quad * 8 + (dt & 1) * 4) = pk;
      }
    }
  }
  __syncthreads();                             // B3: obf written, mbuf reads done
  // stage sigma-plane wlt (32KB) into smem[0..16384) (linear dest)
  for (int rdi = 0; rdi < 8; rdi++) {
    int c = rdi * 256 + tid;
    gl2lds16(wlt + c * 8, smem + c * 8);
  }
  __syncthreads();                             // B4: wlt + obf visible

  int b = bh / 12, hh = bh % 12;
  size_t obase = ((size_t)b * 1024) * 1536 + hh * 128;
  floatx4 cc[2][4] = {};
  for (int kk = 0; kk < 4; kk++) {
    short8 bf[4];
    for (int qg = 0; qg < 4; qg++)
      bf[qg] = *(const short8*)(obf + kk * 2048 + (qg * 16 + ln) * 32 + quad * 8);
    for (int t = 0; t < 2; t++) {
      short8 af = *(const short8*)(smem + kk * 4096 + ((w * 2 + t) * 16 + ln) * 32 + quad * 8);
      for (int qg = 0; qg < 4; qg++)
        cc[t][qg] = MFMA16(af, bf[qg], cc[t][qg]);
    }
  }
  for (int t = 0; t < 2; t++) {
    int c0 = (w * 2 + t) * 16 + quad * 4;
    for (int qg = 0; qg < 4; qg++) {
      int n = qt * 64 + qg * 16 + ln;
      size_t idx = obase + (size_t)n * 1536 + c0;
      uint2 rv = *(const uint2*)(h2res + idx);
      const u16* rvp = (const u16*)&rv;
      u16 tmp[4];
      for (int r = 0; r < 4; r++) {
        float v = cc[t][qg][r] + blp[c0 + r] + b2f(rvp[r]);
        tmp[r] = f2b(gelu_f(v));
      }
      *(uint2*)(feats + idx) = *(const uint2*)tmp;
    }
  }
}

// ------------- host ---------------------------------------------------------------
extern "C" void kernel_launch(void* const* d_in, const int* in_sizes, int n_in,
                              void* d_out, int out_size, void* d_ws, size_t ws_size,
                              hipStream_t stream) {
  (void)in_sizes; (void)n_in; (void)out_size; (void)ws_size;
  const float* x    = (const float*)d_in[0];
  const float* ln1g = (const float*)d_in[1];
  const float* ln1b = (const float*)d_in[2];
  const float* W1   = (const float*)d_in[3];
  const float* b1   = (const float*)d_in[4];
  const float* W2   = (const float*)d_in[5];
  const float* b2   = (const float*)d_in[6];
  const float* alng = (const float*)d_in[7];
  const float* alnb = (const float*)d_in[8];
  const float* Wqkv = (const float*)d_in[9];
  const float* bqkv = (const float*)d_in[10];
  const float* Wl   = (const float*)d_in[11];
  const float* bl   = (const float*)d_in[12];
  const float* lnog = (const float*)d_in[13];
  const float* lnob = (const float*)d_in[14];
  const float* Wo   = (const float*)d_in[15];
  const float* bo   = (const float*)d_in[16];
  float* out = (float*)d_out;

  char* ws = (char*)d_ws;
  size_t off = 0;
  auto alloc = [&](size_t elems) { u16* p = (u16*)(ws + off); off += elems * sizeof(u16); return p; };
  u16* w1t   = alloc((size_t)1536 * 128);
  u16* w2t   = alloc((size_t)1536 * 1536);
  u16* wqkvt = alloc((size_t)384 * 128);
  u16* wlt   = alloc((size_t)128 * 128);
  u16* wot   = alloc((size_t)128 * 1536);
  u16* lnx   = alloc((size_t)4096 * 128);
  u16* h1    = alloc((size_t)4096 * 1536);   // W1-out; then vT; then fp32 pws
  u16* h2    = alloc((size_t)4096 * 1536);
  u16* aln   = alloc((size_t)49152 * 128);   // LN out; then feats
  u16* qkv   = alloc((size_t)49152 * 256);   // q,k only; later lnf
  u16* vT = h1;        // h1 dead after W2 reads it; vT written by qkv_kernel
  u16* feats = aln;    // aln dead after qkv_kernel
  u16* lnf = qkv;      // qkv dead after attn
  float* pws = (float*)h1;  // vT dead after attn; 8 MB <= 12.6 MB

  dim3 T(256);
  tpose_all_kernel<<<dim3(2752), T, 0, stream>>>(W1, W2, Wqkv, Wl, Wo,
                                                 w1t, w2t, wqkvt, wlt, wot);
  // project
  ln128_f32_kernel<<<dim3(4096 / 4), T, 0, stream>>>(x, ln1g, ln1b, lnx);
  gemm64_kernel<1, 0, u16><<<dim3(4096 / 64, 1536 / 128), T, 0, stream>>>(
      lnx, w1t, b1, nullptr, h1, 4096, 1536, 128);
  // W2 GEMM with FUSED per-head LN (writes h2 AND aln; replaces ln128_perm)
  gemm64b_ln_kernel<<<dim3(4096 / 64, 1536 / 128), T, 0, stream>>>(
      h1, w2t, b2, h2, alng, alnb, aln, 4096, 1536, 1536);
  // attention: QKV GEMM (V direct to vT) -> attn + fused Wl epilogue
  qkv_kernel<<<dim3(49152 / 128, 3), T, 0, stream>>>(aln, wqkvt, bqkv, qkv, vT);
  attn_kernel<<<dim3(768), T, 0, stream>>>(qkv, vT, wlt, bl, h2, feats);
  // out_proj: LN1536 -> split-K x4 -> combine
  ln1536_kernel<<<dim3(4096), T, 0, stream>>>(feats, lnog, lnob, lnf);
  gemm64_part_kernel<<<dim3(4096 / 64, 4), T, 0, stream>>>(lnf, wot, pws, 1536, 384);
  combine_wo_kernel<<<dim3(4096 * 128 / 256), T, 0, stream>>>(pws, bo, out);
}

// Round 20
// 222.472 us; speedup vs baseline: 1.0844x; 1.0844x over previous
//
#include <hip/hip_runtime.h>
#include <stdint.h>

typedef unsigned short u16;
typedef __attribute__((ext_vector_type(8))) short short8;   // 8 bf16 (MFMA A/B frag)
typedef __attribute__((ext_vector_type(4))) float floatx4;  // MFMA C/D frag

__device__ inline float b2f(u16 u) {
  union { uint32_t i; float f; } x; x.i = ((uint32_t)u) << 16; return x.f;
}
__device__ inline u16 f2b(float f) {
  union { float f; uint32_t i; } x; x.f = f;
  uint32_t r = (x.i + 0x7FFFu + ((x.i >> 16) & 1u)) >> 16;
  return (u16)r;
}
__device__ inline float gelu_f(float v) {
  return 0.5f * v * (1.0f + erff(v * 0.70710678118654752440f));
}

#define MFMA16(a, b, c) __builtin_amdgcn_mfma_f32_16x16x32_bf16((a), (b), (c), 0, 0, 0)

// async global->LDS, 16B per lane; LDS dest must be wave-uniform base + lane*16
__device__ __forceinline__ void gl2lds16(const u16* g, u16* l) {
  __builtin_amdgcn_global_load_lds(
      (const __attribute__((address_space(1))) uint32_t*)(uintptr_t)g,
      (__attribute__((address_space(3))) uint32_t*)(uint32_t)(uintptr_t)l,
      16, 0, 0);
}

// ------------- batched transpose+convert of all 5 weights (fp32 -> bf16^T) -------
// Wl is stored SIGMA-PLANE ordered: wlt[(d>>5)*4096 + c*32 + sig(d&31)] so the
// fused attn epilogue can read A-fragments from 32-k planes (kbuf pattern) and
// stage it linearly via global_load_lds.
__global__ __launch_bounds__(256)
void tpose_all_kernel(const float* __restrict__ W1, const float* __restrict__ W2,
                      const float* __restrict__ Wqkv, const float* __restrict__ Wl,
                      const float* __restrict__ Wo,
                      u16* __restrict__ w1t, u16* __restrict__ w2t,
                      u16* __restrict__ wqkvt, u16* __restrict__ wlt,
                      u16* __restrict__ wot) {
  int id = blockIdx.x;
  const float* src; u16* dst; int R, C, bx, by, kind = 0;
  if (id < 2304)      { src = W2;   dst = w2t;   R = 1536; C = 1536; bx = (id % 48) * 32; by = (id / 48) * 32; }
  else if (id < 2496) { id -= 2304; src = W1;   dst = w1t;   R = 128;  C = 1536; bx = (id % 48) * 32; by = (id / 48) * 32; }
  else if (id < 2688) { id -= 2496; src = Wo;   dst = wot;   R = 1536; C = 128;  bx = (id % 4) * 32;  by = (id / 4) * 32; }
  else if (id < 2736) { id -= 2688; src = Wqkv; dst = wqkvt; R = 128;  C = 384;  bx = (id % 12) * 32; by = (id / 12) * 32; }
  else                { id -= 2736; src = Wl;   dst = wlt;   R = 128;  C = 128;  bx = (id % 4) * 32;  by = (id / 4) * 32; kind = 1; }
  __shared__ u16 t[32][33];
  int tx = threadIdx.x & 31, ty = threadIdx.x >> 5;
  for (int i = 0; i < 32; i += 8)
    t[ty + i][tx] = f2b(src[(size_t)(by + ty + i) * C + bx + tx]);
  __syncthreads();
  if (kind == 0) {
    for (int i = 0; i < 32; i += 8)
      dst[(size_t)(bx + ty + i) * R + by + tx] = t[tx][ty + i];
  } else {
    // value = Wl[d=by+tx][c=bx+ty+i] -> plane (by>>5), row c, pos sig(tx)
    int sig = ((tx >> 2) & 3) * 8 + ((tx >> 4) & 1) * 4 + (tx & 3);
    for (int i = 0; i < 32; i += 8)
      dst[(size_t)(by >> 5) * 4096 + (size_t)(bx + ty + i) * 32 + sig] = t[tx][ty + i];
  }
}

// ------------- LayerNorm D=128, fp32 source -> bf16 out; one wave per row ---------
__global__ __launch_bounds__(256)
void ln128_f32_kernel(const float* __restrict__ X, const float* __restrict__ g,
                      const float* __restrict__ bb, u16* __restrict__ Y) {
  int tid = threadIdx.x, w = tid >> 6, lane = tid & 63;
  int row = blockIdx.x * 4 + w;
  const float* xr = X + (size_t)row * 128;
  float2 xv = *(const float2*)(xr + lane * 2);
  float x0 = xv.x, x1 = xv.y;
  float s = x0 + x1, s2 = x0 * x0 + x1 * x1;
  for (int m = 1; m < 64; m <<= 1) { s += __shfl_xor(s, m, 64); s2 += __shfl_xor(s2, m, 64); }
  float mean = s * (1.0f / 128.0f);
  float var = s2 * (1.0f / 128.0f) - mean * mean;
  float rstd = 1.0f / sqrtf(var + 1e-5f);
  float2 gv = *(const float2*)(g + lane * 2);
  float2 bv = *(const float2*)(bb + lane * 2);
  float y0 = (x0 - mean) * rstd * gv.x + bv.x;
  float y1 = (x1 - mean) * rstd * gv.y + bv.y;
  *(uint32_t*)(Y + (size_t)row * 128 + lane * 2) =
      (uint32_t)f2b(y0) | ((uint32_t)f2b(y1) << 16);
}

// ------------- LayerNorm D=1536, bf16 source -> bf16 out; one block per row -------
__global__ __launch_bounds__(256)
void ln1536_kernel(const u16* __restrict__ X, const float* __restrict__ g,
                   const float* __restrict__ bb, u16* __restrict__ Y) {
  int row = blockIdx.x, tid = threadIdx.x;
  const u16* xr = X + (size_t)row * 1536;
  uint32_t u0 = *(const uint32_t*)(xr + tid * 6);
  uint32_t u1 = *(const uint32_t*)(xr + tid * 6 + 2);
  uint32_t u2 = *(const uint32_t*)(xr + tid * 6 + 4);
  float v[6] = { b2f(u0 & 0xffff), b2f(u0 >> 16), b2f(u1 & 0xffff),
                 b2f(u1 >> 16),    b2f(u2 & 0xffff), b2f(u2 >> 16) };
  float s = 0.f, s2 = 0.f;
  for (int j = 0; j < 6; j++) { s += v[j]; s2 += v[j] * v[j]; }
  for (int m = 1; m < 64; m <<= 1) { s += __shfl_xor(s, m, 64); s2 += __shfl_xor(s2, m, 64); }
  __shared__ float red[8];
  int w = tid >> 6, lane = tid & 63;
  if (lane == 0) { red[w] = s; red[4 + w] = s2; }
  __syncthreads();
  s = red[0] + red[1] + red[2] + red[3];
  s2 = red[4] + red[5] + red[6] + red[7];
  float mean = s * (1.0f / 1536.0f);
  float var = s2 * (1.0f / 1536.0f) - mean * mean;
  float rstd = 1.0f / sqrtf(var + 1e-5f);
  uint32_t o[3];
  for (int p = 0; p < 3; p++) {
    int c = tid * 6 + p * 2;
    float y0 = (v[p * 2] - mean) * rstd * g[c] + bb[c];
    float y1 = (v[p * 2 + 1] - mean) * rstd * g[c + 1] + bb[c + 1];
    o[p] = (uint32_t)f2b(y0) | ((uint32_t)f2b(y1) << 16);
  }
  u16* yr = Y + (size_t)row * 1536 + tid * 6;
  *(uint32_t*)(yr) = o[0];
  *(uint32_t*)(yr + 2) = o[1];
  *(uint32_t*)(yr + 4) = o[2];
}

// ------------- QKV GEMM 128x128 tile, PIPELINED (dbuf, single barrier/K-step) -----
__global__ __launch_bounds__(256)
void qkv_kernel(const u16* __restrict__ A, const u16* __restrict__ BT,
                const float* __restrict__ bias, u16* __restrict__ qkv,
                u16* __restrict__ vT) {
  const int K = 128;
  __shared__ __align__(16) u16 abuf[2 * 128 * 32];
  __shared__ __align__(16) u16 bbuf[2 * 128 * 32];
  int tid = threadIdx.x;
  int w = tid >> 6, lane = tid & 63, ln = lane & 15, quad = lane >> 4;
  int bm = blockIdx.x * 128, bn = blockIdx.y * 128;
  int wr = w >> 1, wc = w & 1;
  floatx4 acc[4][4] = {};
  auto STAGE = [&](int k0, int buf) {
    u16* ab = abuf + buf * 4096;
    u16* bb = bbuf + buf * 4096;
    for (int rd = 0; rd < 2; rd++) {
      int c = tid + rd * 256;
      int row = c >> 2, col = (c & 3) * 8;
      gl2lds16(A + (size_t)(bm + row) * K + k0 + col, ab + c * 8);
      gl2lds16(BT + (size_t)(bn + row) * K + k0 + col, bb + c * 8);
    }
  };
  STAGE(0, 0);
  int it = 0;
  for (int k0 = 0; k0 < K; k0 += 32, it++) {
    __syncthreads();                      // staged tile (it&1) ready
    if (k0 + 32 < K) STAGE(k0 + 32, (it + 1) & 1);
    const u16* ab = abuf + (it & 1) * 4096;
    const u16* bb = bbuf + (it & 1) * 4096;
    short8 af[4], bf[4];
    for (int i = 0; i < 4; i++)
      af[i] = *(const short8*)(ab + (wr * 64 + i * 16 + ln) * 32 + quad * 8);
    for (int j = 0; j < 4; j++)
      bf[j] = *(const short8*)(bb + (wc * 64 + j * 16 + ln) * 32 + quad * 8);
    for (int i = 0; i < 4; i++)
      for (int j = 0; j < 4; j++)
        acc[i][j] = MFMA16(af[i], bf[j], acc[i][j]);
  }
  if (blockIdx.y < 2) {
    const float QSCALE = 0.08838834764831845f * 1.4426950408889634f;
    float scale = (blockIdx.y == 0) ? QSCALE : 1.0f;
    for (int i = 0; i < 4; i++) {
      int row0 = bm + wr * 64 + i * 16 + quad * 4;
      for (int j = 0; j < 4; j++) {
        int col = bn + wc * 64 + j * 16 + ln;
        float bv = bias[col];
        for (int r = 0; r < 4; r++)
          qkv[(size_t)(row0 + r) * 256 + col] = f2b((acc[i][j][r] + bv) * scale);
      }
    }
  } else {
    int bh = bm >> 10;                 // block fully inside one (b,h): 1024 rows/bh
    int nb = bm & 1023;
    u16* vp = vT + (size_t)bh * 128 * 1024;
    for (int i = 0; i < 4; i++) {
      int n0 = nb + wr * 64 + i * 16 + quad * 4;
      // sigma-interleaved position within the 32-key group:
      int npos = (n0 & ~31) | (((n0 >> 2) & 3) * 8) | (((n0 >> 4) & 1) * 4);
      for (int j = 0; j < 4; j++) {
        int d = wc * 64 + j * 16 + ln;
        float bv = bias[256 + d];
        u16 tmp[4];
        for (int r = 0; r < 4; r++) tmp[r] = f2b(acc[i][j][r] + bv);
        *(uint2*)(vp + (size_t)d * 1024 + npos) = *(const uint2*)tmp;
      }
    }
  }
}

// ------------- GEMM 64x128 tile, BK=32 (W1), PIPELINED ----------------------------
template <int GELU, int RES, typename OUTT>
__global__ __launch_bounds__(256)
void gemm64_kernel(const u16* __restrict__ A, const u16* __restrict__ BT,
                   const float* __restrict__ bias, const u16* __restrict__ res,
                   OUTT* __restrict__ C, int M, int N, int K) {
  __shared__ __align__(16) u16 abuf[2 * 64 * 32];
  __shared__ __align__(16) u16 bbuf[2 * 128 * 32];
  int tid = threadIdx.x;
  int w = tid >> 6, lane = tid & 63, ln = lane & 15, quad = lane >> 4;
  int bm = blockIdx.x * 64, bn = blockIdx.y * 128;
  floatx4 acc[4][2] = {};
  auto STAGE = [&](int k0, int buf) {
    u16* ab = abuf + buf * 2048;
    u16* bb = bbuf + buf * 4096;
    for (int rd = 0; rd < 2; rd++) {
      int c = tid + rd * 256;
      int row = c >> 2, col = (c & 3) * 8;
      gl2lds16(BT + (size_t)(bn + row) * K + k0 + col, bb + c * 8);
    }
    {
      int c = tid;
      int row = c >> 2, col = (c & 3) * 8;
      gl2lds16(A + (size_t)(bm + row) * K + k0 + col, ab + c * 8);
    }
  };
  STAGE(0, 0);
  int it = 0;
  for (int k0 = 0; k0 < K; k0 += 32, it++) {
    __syncthreads();
    if (k0 + 32 < K) STAGE(k0 + 32, (it + 1) & 1);
    const u16* ab = abuf + (it & 1) * 2048;
    const u16* bb = bbuf + (it & 1) * 4096;
    short8 af[4], bf[2];
    for (int i = 0; i < 4; i++)
      af[i] = *(const short8*)(ab + (i * 16 + ln) * 32 + quad * 8);
    for (int j = 0; j < 2; j++)
      bf[j] = *(const short8*)(bb + (w * 32 + j * 16 + ln) * 32 + quad * 8);
    for (int i = 0; i < 4; i++)
      for (int j = 0; j < 2; j++)
        acc[i][j] = MFMA16(af[i], bf[j], acc[i][j]);
  }
  for (int i = 0; i < 4; i++) {
    int row0 = bm + i * 16 + quad * 4;
    for (int j = 0; j < 2; j++) {
      int col = bn + w * 32 + j * 16 + ln;
      float bv = bias[col];
      for (int r = 0; r < 4; r++) {
        float v = acc[i][j][r] + bv;
        if (RES) v += b2f(res[(size_t)(row0 + r) * N + col]);
        if (GELU) v = gelu_f(v);
        if constexpr (sizeof(OUTT) == 2)
          C[(size_t)(row0 + r) * N + col] = f2b(v);
        else
          C[(size_t)(row0 + r) * N + col] = v;
      }
    }
  }
}

// ------------- GEMM 64x128 tile, BK=64 (W2), PIPELINED + FUSED per-head LN --------
__global__ __launch_bounds__(256)
void gemm64b_ln_kernel(const u16* __restrict__ A, const u16* __restrict__ BT,
                       const float* __restrict__ bias, u16* __restrict__ C,
                       const float* __restrict__ lng, const float* __restrict__ lnb,
                       u16* __restrict__ aln, int M, int N, int K) {
  __shared__ __align__(16) u16 abuf[2 * 2 * 64 * 32];
  __shared__ __align__(16) u16 bbuf[2 * 2 * 128 * 32];
  int tid = threadIdx.x;
  int w = tid >> 6, lane = tid & 63, ln = lane & 15, quad = lane >> 4;
  int bm = blockIdx.x * 64, bn = blockIdx.y * 128;
  floatx4 acc[4][2] = {};
  auto STAGE = [&](int k0, int buf) {
    u16* ab = abuf + buf * 4096;
    u16* bb = bbuf + buf * 8192;
    for (int ks = 0; ks < 2; ks++) {
      {
        int c = tid;
        int row = c >> 2, cc = c & 3;
        gl2lds16(A + (size_t)(bm + row) * K + k0 + ks * 32 + cc * 8,
                 ab + ks * 2048 + c * 8);
      }
      for (int rd = 0; rd < 2; rd++) {
        int c = tid + rd * 256;
        int row = c >> 2, cc = c & 3;
        gl2lds16(BT + (size_t)(bn + row) * K + k0 + ks * 32 + cc * 8,
                 bb + ks * 4096 + c * 8);
      }
    }
  };
  STAGE(0, 0);
  int it = 0;
  for (int k0 = 0; k0 < K; k0 += 64, it++) {
    __syncthreads();
    if (k0 + 64 < K) STAGE(k0 + 64, (it + 1) & 1);
    const u16* ab = abuf + (it & 1) * 4096;
    const u16* bb = bbuf + (it & 1) * 8192;
    short8 af[2][4], bf[2][2];
    for (int ks = 0; ks < 2; ks++) {
      for (int i = 0; i < 4; i++)
        af[ks][i] = *(const short8*)(ab + ks * 2048 + (i * 16 + ln) * 32 + quad * 8);
      for (int j = 0; j < 2; j++)
        bf[ks][j] = *(const short8*)(bb + ks * 4096 + (w * 32 + j * 16 + ln) * 32 + quad * 8);
    }
    for (int i = 0; i < 4; i++)
      for (int j = 0; j < 2; j++) {
        acc[i][j] = MFMA16(af[0][i], bf[0][j], acc[i][j]);
        acc[i][j] = MFMA16(af[1][i], bf[1][j], acc[i][j]);
      }
  }
  // epilogue: write h2 (bf16) + fused per-head LN -> aln
  float vr[4][2][4];
  float sl[16], s2l[16];
  for (int t = 0; t < 16; t++) { sl[t] = 0.f; s2l[t] = 0.f; }
  float g0 = lng[w * 32 + ln], g1 = lng[w * 32 + 16 + ln];
  float bb0 = lnb[w * 32 + ln], bb1 = lnb[w * 32 + 16 + ln];
  for (int i = 0; i < 4; i++) {
    int row0 = bm + i * 16 + quad * 4;
    for (int j = 0; j < 2; j++) {
      int col = bn + w * 32 + j * 16 + ln;
      float bv = bias[col];
      for (int r = 0; r < 4; r++) {
        u16 hb = f2b(acc[i][j][r] + bv);
        C[(size_t)(row0 + r) * N + col] = hb;
        float x = b2f(hb);
        vr[i][j][r] = x;
        sl[i * 4 + r] += x;
        s2l[i * 4 + r] += x * x;
      }
    }
  }
  // reduce over ln (stays within quad: masks < 16)
  for (int m = 1; m < 16; m <<= 1)
    for (int t = 0; t < 16; t++) {
      sl[t] += __shfl_xor(sl[t], m, 64);
      s2l[t] += __shfl_xor(s2l[t], m, 64);
    }
  // cross-wave reduce via LDS (abuf dead; ensure all waves done reading frags)
  __syncthreads();
  float* red = (float*)abuf;                 // [2][4 w][64 row] = 2KB
  if (ln == 0) {
    for (int i = 0; i < 4; i++)
      for (int r = 0; r < 4; r++) {
        int row = i * 16 + quad * 4 + r;
        red[w * 64 + row] = sl[i * 4 + r];
        red[256 + w * 64 + row] = s2l[i * 4 + r];
      }
  }
  __syncthreads();
  int hh = bn >> 7;
  for (int i = 0; i < 4; i++) {
    int row0 = bm + i * 16 + quad * 4;
    int rowl = i * 16 + quad * 4;
    for (int r = 0; r < 4; r++) {
      float s = red[rowl + r] + red[64 + rowl + r] + red[128 + rowl + r] + red[192 + rowl + r];
      float s2 = red[256 + rowl + r] + red[320 + rowl + r] + red[384 + rowl + r] + red[448 + rowl + r];
      float mean = s * (1.0f / 128.0f);
      float var = s2 * (1.0f / 128.0f) - mean * mean;
      float rstd = 1.0f / sqrtf(var + 1e-5f);
      int rw = row0 + r, b = rw >> 10, n = rw & 1023;
      size_t arow = ((size_t)(b * 12 + hh) * 1024 + n) * 128;
      float y0 = (vr[i][0][r] - mean) * rstd * g0 + bb0;
      float y1 = (vr[i][1][r] - mean) * rstd * g1 + bb1;
      aln[arow + w * 32 + ln] = f2b(y0);
      aln[arow + w * 32 + 16 + ln] = f2b(y1);
    }
  }
}

// ------------- Wo split-K partial: 64x128 tile, part p = blockIdx.y, PIPELINED ----
__global__ __launch_bounds__(256)
void gemm64_part_kernel(const u16* __restrict__ A, const u16* __restrict__ BT,
                        float* __restrict__ pws, int Kfull, int kspan) {
  __shared__ __align__(16) u16 abuf[2 * 64 * 32];
  __shared__ __align__(16) u16 bbuf[2 * 128 * 32];
  int tid = threadIdx.x;
  int w = tid >> 6, lane = tid & 63, ln = lane & 15, quad = lane >> 4;
  int bm = blockIdx.x * 64;
  int kbeg = blockIdx.y * kspan, kend = kbeg + kspan;
  float* Cp = pws + (size_t)blockIdx.y * 4096 * 128;
  floatx4 acc[4][2] = {};
  auto STAGE = [&](int k0, int buf) {
    u16* ab = abuf + buf * 2048;
    u16* bb = bbuf + buf * 4096;
    for (int rd = 0; rd < 2; rd++) {
      int c = tid + rd * 256;
      int row = c >> 2, col = (c & 3) * 8;
      gl2lds16(BT + (size_t)row * Kfull + k0 + col, bb + c * 8);
    }
    {
      int c = tid;
      int row = c >> 2, col = (c & 3) * 8;
      gl2lds16(A + (size_t)(bm + row) * Kfull + k0 + col, ab + c * 8);
    }
  };
  STAGE(kbeg, 0);
  int it = 0;
  for (int k0 = kbeg; k0 < kend; k0 += 32, it++) {
    __syncthreads();
    if (k0 + 32 < kend) STAGE(k0 + 32, (it + 1) & 1);
    const u16* ab = abuf + (it & 1) * 2048;
    const u16* bb = bbuf + (it & 1) * 4096;
    short8 af[4], bf[2];
    for (int i = 0; i < 4; i++)
      af[i] = *(const short8*)(ab + (i * 16 + ln) * 32 + quad * 8);
    for (int j = 0; j < 2; j++)
      bf[j] = *(const short8*)(bb + (w * 32 + j * 16 + ln) * 32 + quad * 8);
    for (int i = 0; i < 4; i++)
      for (int j = 0; j < 2; j++)
        acc[i][j] = MFMA16(af[i], bf[j], acc[i][j]);
  }
  for (int i = 0; i < 4; i++) {
    int row0 = bm + i * 16 + quad * 4;
    for (int j = 0; j < 2; j++) {
      int col = w * 32 + j * 16 + ln;
      for (int r = 0; r < 4; r++)
        Cp[(size_t)(row0 + r) * 128 + col] = acc[i][j][r];
    }
  }
}

// combine 4 split-K partials + bias + gelu -> fp32 out  (4096*128 elems)
__global__ __launch_bounds__(256)
void combine_wo_kernel(const float* __restrict__ p, const float* __restrict__ bias,
                       float* __restrict__ out) {
  int i = blockIdx.x * 256 + threadIdx.x;
  const int SZ = 4096 * 128;
  float v = p[i] + p[i + SZ] + p[i + 2 * SZ] + p[i + 3 * SZ] + bias[i & 127];
  out[i] = gelu_f(v);
}

// ------------- Flash attention + FUSED Wl GEMM epilogue --------------------------
// Main loop: round-11 verified. Epilogue computes feats = gelu(O*Wl + bias + res).
// wlt (sigma-plane) staged via LDS at B3/B4. (Round-19's setprio markers caused
// regalloc spills -> reverted; this is the round-18 verified best build.)
__global__ __launch_bounds__(256, 3)
void attn_kernel(const u16* __restrict__ qkv, const u16* __restrict__ vT,
                 const u16* __restrict__ wlt, const float* __restrict__ blp,
                 const u16* __restrict__ h2res, u16* __restrict__ feats) {
  int blk = blockIdx.x;
  int xcd = blk & 7, slot = blk >> 3;
  int bh = xcd * 6 + (slot >> 4);
  int qt = slot & 15;
  int tid = threadIdx.x, w = tid >> 6, lane = tid & 63, ln = lane & 15, quad = lane >> 4;
  int pair = w & 1, half = w >> 1;
  __shared__ __align__(16) u16 smem[24576 + 128];
  u16* kbuf = smem;                   // [4 st][64 key][32]
  u16* vbufs = smem + 8192;           // 2 x [2 kf][128 d][32 pos] (sigma order)
  const int rs = 256;
  size_t base = (size_t)bh * 1024 * 256;
  const u16* qp = qkv + base;
  const u16* kp = qkv + base + 128;
  const u16* vp = vT + (size_t)bh * 128 * 1024;

  // Q fragments for this wave's 32 q rows (2 groups of 16)
  short8 qf[2][4];
  for (int g = 0; g < 2; g++) {
    int qrow = qt * 64 + pair * 32 + g * 16 + ln;
    for (int st = 0; st < 4; st++)
      qf[g][st] = *(const short8*)(qp + (size_t)qrow * rs + st * 32 + quad * 8);
  }

  // ones A-row fragment: A[0][k]=1 (lanes with ln==0), other rows 0.
  short8 onesA;
  {
    short v = (ln == 0) ? (short)0x3F80 : (short)0;
    for (int j = 0; j < 8; j++) onesA[j] = v;
  }

  floatx4 o[2][8] = {};             // O^T partial: [g][dt], row=d quad*4+r, col=q=ln
  floatx4 l9[2] = {};               // row0 = per-q P-sums (ones-MFMA)

  // staging helpers: 4 chunks each per thread per tile (all linear)
  auto STAGE_K = [&](int kt) {
    for (int it = 0; it < 4; it++) {
      int c = it * 256 + tid;
      int st = c >> 8, key = (c >> 2) & 63, cc = c & 3;
      gl2lds16(kp + (size_t)(kt * 64 + key) * rs + st * 32 + cc * 8, kbuf + c * 8);
    }
  };
  auto STAGE_V = [&](int kt, int buf) {
    u16* vb = vbufs + buf * 8192;
    for (int it = 0; it < 4; it++) {
      int c = it * 256 + tid;
      int kf = c >> 9, d = (c >> 2) & 127, cc = c & 3;
      gl2lds16(vp + (size_t)d * 1024 + kt * 64 + kf * 32 + cc * 8, vb + c * 8);
    }
  };

  STAGE_K(0);
  STAGE_V(0, 0);

  for (int kt = 0; kt < 16; kt++) {
    __syncthreads();                 // drains vmcnt(0): staging for kt complete

    // K fragments -> registers (frees kbuf for next-tile staging)
    short8 kfr[2][4];
    for (int tt = 0; tt < 2; tt++)
      for (int st = 0; st < 4; st++)
        kfr[tt][st] = *(const short8*)(kbuf + st * 2048 +
                                       ((half * 2 + tt) * 16 + ln) * 32 + quad * 8);
    __syncthreads();                 // all waves done reading kbuf (lgkm drained)

    if (kt < 15) {                   // async staging overlaps the compute below
      STAGE_K(kt + 1);
      STAGE_V(kt + 1, (kt + 1) & 1);
    }

    // S^T tiles from registers (q pre-scaled -> S already in log2 units)
    floatx4 s[2][2] = {};            // [g][tt]
    for (int tt = 0; tt < 2; tt++)
      for (int st = 0; st < 4; st++) {
        s[0][tt] = MFMA16(kfr[tt][st], qf[0][st], s[0][tt]);
        s[1][tt] = MFMA16(kfr[tt][st], qf[1][st], s[1][tt]);
      }

    // exp2 -> packed bf16; natural order IS the PV B-operand (sigma ordering)
    short8 pfrag[2];
    for (int g = 0; g < 2; g++) {
      float p0[4], p1[4];
      for (int r = 0; r < 4; r++) {
        p0[r] = exp2f(s[g][0][r]);
        p1[r] = exp2f(s[g][1][r]);
      }
      uint32_t a0, a1, b0, b1;
      asm("v_cvt_pk_bf16_f32 %0, %1, %2" : "=v"(a0) : "v"(p0[0]), "v"(p0[1]));
      asm("v_cvt_pk_bf16_f32 %0, %1, %2" : "=v"(a1) : "v"(p0[2]), "v"(p0[3]));
      asm("v_cvt_pk_bf16_f32 %0, %1, %2" : "=v"(b0) : "v"(p1[0]), "v"(p1[1]));
      asm("v_cvt_pk_bf16_f32 %0, %1, %2" : "=v"(b1) : "v"(p1[2]), "v"(p1[3]));
      union { uint32_t u[4]; short8 v; } pu;
      pu.u[0] = a0; pu.u[1] = a1; pu.u[2] = b0; pu.u[3] = b1;
      pfrag[g] = pu.v;
    }

    // row-sums on the MFMA pipe
    l9[0] = MFMA16(onesA, pfrag[0], l9[0]);
    l9[1] = MFMA16(onesA, pfrag[1], l9[1]);

    // PV: single b128 V^T A-fragment (vT stored in sigma order)
    const u16* vb = vbufs + (kt & 1) * 8192;
    for (int dt = 0; dt < 8; dt++) {
      short8 av = *(const short8*)(vb + half * 4096 + (dt * 16 + ln) * 32 + quad * 8);
      o[0][dt] = MFMA16(av, pfrag[0], o[0][dt]);
      o[1][dt] = MFMA16(av, pfrag[1], o[1][dt]);
    }
  }

  // per-q row-sums live at quad0/r0, col=ln -> broadcast from lane ln
  float lsum[2];
  lsum[0] = __shfl(l9[0][0], ln);
  lsum[1] = __shfl(l9[1][0], ln);

  // ---- merge key-halves, then fused Wl GEMM ----
  __syncthreads();                             // B1: kbuf/vbuf dead
  float* mbuf = (float*)smem;                  // [2 pair][128 d][32 q(rot)] 32KB
  float* lbuf = (float*)(smem + 16384);        // 256B at byte 32768
  u16* obf = smem + 16512;                     // 4 planes x [64 q][32 pos] 16KB
  if (half == 1) {
    float* mp = mbuf + pair * 4096;
    for (int g = 0; g < 2; g++)
      for (int dt = 0; dt < 8; dt++)
        for (int r = 0; r < 4; r++)
          mp[(dt * 16 + quad * 4 + r) * 32 + ((g * 16 + ln + quad * 8) & 31)] = o[g][dt][r];
    if (quad == 0) {
      lbuf[pair * 32 + ln] = lsum[0];
      lbuf[pair * 32 + 16 + ln] = lsum[1];
    }
  }
  __syncthreads();                             // B2: mbuf/lbuf ready
  if (half == 0) {
    float* mp = mbuf + pair * 4096;
    for (int g = 0; g < 2; g++) {
      float lt = lsum[g] + lbuf[pair * 32 + g * 16 + ln];
      float inv = 1.0f / lt;
      int q = pair * 32 + g * 16 + ln;
      for (int dt = 0; dt < 8; dt++) {
        float vv[4];
        for (int r = 0; r < 4; r++)
          vv[r] = (o[g][dt][r] +
                   mp[(dt * 16 + quad * 4 + r) * 32 + ((g * 16 + ln + quad * 8) & 31)]) * inv;
        uint32_t w0, w1;
        asm("v_cvt_pk_bf16_f32 %0, %1, %2" : "=v"(w0) : "v"(vv[0]), "v"(vv[1]));
        asm("v_cvt_pk_bf16_f32 %0, %1, %2" : "=v"(w1) : "v"(vv[2]), "v"(vv[3]));
        uint2 pk; pk.x = w0; pk.y = w1;
        // plane kk=dt>>1, row q, pos quad*8 + (dt&1)*4  (sigma-local of d)
        *(uint2*)(obf + (dt >> 1) * 2048 + q * 32 + quad * 8 + (dt & 1) * 4) = pk;
      }
    }
  }
  __syncthreads();                             // B3: obf written, mbuf reads done
  // stage sigma-plane wlt (32KB) into smem[0..16384) (linear dest)
  for (int rdi = 0; rdi < 8; rdi++) {
    int c = rdi * 256 + tid;
    gl2lds16(wlt + c * 8, smem + c * 8);
  }
  __syncthreads();                             // B4: wlt + obf visible

  int b = bh / 12, hh = bh % 12;
  size_t obase = ((size_t)b * 1024) * 1536 + hh * 128;
  floatx4 cc[2][4] = {};
  for (int kk = 0; kk < 4; kk++) {
    short8 bf[4];
    for (int qg = 0; qg < 4; qg++)
      bf[qg] = *(const short8*)(obf + kk * 2048 + (qg * 16 + ln) * 32 + quad * 8);
    for (int t = 0; t < 2; t++) {
      short8 af = *(const short8*)(smem + kk * 4096 + ((w * 2 + t) * 16 + ln) * 32 + quad * 8);
      for (int qg = 0; qg < 4; qg++)
        cc[t][qg] = MFMA16(af, bf[qg], cc[t][qg]);
    }
  }
  for (int t = 0; t < 2; t++) {
    int c0 = (w * 2 + t) * 16 + quad * 4;
    for (int qg = 0; qg < 4; qg++) {
      int n = qt * 64 + qg * 16 + ln;
      size_t idx = obase + (size_t)n * 1536 + c0;
      uint2 rv = *(const uint2*)(h2res + idx);
      const u16* rvp = (const u16*)&rv;
      u16 tmp[4];
      for (int r = 0; r < 4; r++) {
        float v = cc[t][qg][r] + blp[c0 + r] + b2f(rvp[r]);
        tmp[r] = f2b(gelu_f(v));
      }
      *(uint2*)(feats + idx) = *(const uint2*)tmp;
    }
  }
}

// ------------- host ---------------------------------------------------------------
extern "C" void kernel_launch(void* const* d_in, const int* in_sizes, int n_in,
                              void* d_out, int out_size, void* d_ws, size_t ws_size,
                              hipStream_t stream) {
  (void)in_sizes; (void)n_in; (void)out_size; (void)ws_size;
  const float* x    = (const float*)d_in[0];
  const float* ln1g = (const float*)d_in[1];
  const float* ln1b = (const float*)d_in[2];
  const float* W1   = (const float*)d_in[3];
  const float* b1   = (const float*)d_in[4];
  const float* W2   = (const float*)d_in[5];
  const float* b2   = (const float*)d_in[6];
  const float* alng = (const float*)d_in[7];
  const float* alnb = (const float*)d_in[8];
  const float* Wqkv = (const float*)d_in[9];
  const float* bqkv = (const float*)d_in[10];
  const float* Wl   = (const float*)d_in[11];
  const float* bl   = (const float*)d_in[12];
  const float* lnog = (const float*)d_in[13];
  const float* lnob = (const float*)d_in[14];
  const float* Wo   = (const float*)d_in[15];
  const float* bo   = (const float*)d_in[16];
  float* out = (float*)d_out;

  char* ws = (char*)d_ws;
  size_t off = 0;
  auto alloc = [&](size_t elems) { u16* p = (u16*)(ws + off); off += elems * sizeof(u16); return p; };
  u16* w1t   = alloc((size_t)1536 * 128);
  u16* w2t   = alloc((size_t)1536 * 1536);
  u16* wqkvt = alloc((size_t)384 * 128);
  u16* wlt   = alloc((size_t)128 * 128);
  u16* wot   = alloc((size_t)128 * 1536);
  u16* lnx   = alloc((size_t)4096 * 128);
  u16* h1    = alloc((size_t)4096 * 1536);   // W1-out; then vT; then fp32 pws
  u16* h2    = alloc((size_t)4096 * 1536);
  u16* aln   = alloc((size_t)49152 * 128);   // LN out; then feats
  u16* qkv   = alloc((size_t)49152 * 256);   // q,k only; later lnf
  u16* vT = h1;        // h1 dead after W2 reads it; vT written by qkv_kernel
  u16* feats = aln;    // aln dead after qkv_kernel
  u16* lnf = qkv;      // qkv dead after attn
  float* pws = (float*)h1;  // vT dead after attn; 8 MB <= 12.6 MB

  dim3 T(256);
  tpose_all_kernel<<<dim3(2752), T, 0, stream>>>(W1, W2, Wqkv, Wl, Wo,
                                                 w1t, w2t, wqkvt, wlt, wot);
  // project
  ln128_f32_kernel<<<dim3(4096 / 4), T, 0, stream>>>(x, ln1g, ln1b, lnx);
  gemm64_kernel<1, 0, u16><<<dim3(4096 / 64, 1536 / 128), T, 0, stream>>>(
      lnx, w1t, b1, nullptr, h1, 4096, 1536, 128);
  // W2 GEMM with FUSED per-head LN (writes h2 AND aln; replaces ln128_perm)
  gemm64b_ln_kernel<<<dim3(4096 / 64, 1536 / 128), T, 0, stream>>>(
      h1, w2t, b2, h2, alng, alnb, aln, 4096, 1536, 1536);
  // attention: QKV GEMM (V direct to vT) -> attn + fused Wl epilogue
  qkv_kernel<<<dim3(49152 / 128, 3), T, 0, stream>>>(aln, wqkvt, bqkv, qkv, vT);
  attn_kernel<<<dim3(768), T, 0, stream>>>(qkv, vT, wlt, bl, h2, feats);
  // out_proj: LN1536 -> split-K x4 -> combine
  ln1536_kernel<<<dim3(4096), T, 0, stream>>>(feats, lnog, lnob, lnf);
  gemm64_part_kernel<<<dim3(4096 / 64, 4), T, 0, stream>>>(lnf, wot, pws, 1536, 384);
  combine_wo_kernel<<<dim3(4096 * 128 / 256), T, 0, stream>>>(pws, bo, out);
}